// Round 1
// baseline (529.672 us; speedup 1.0000x reference)
//
#include <hip/hip_runtime.h>
#include <hip/hip_bf16.h>
#include <math.h>

// Problem constants
#define LDIM 4096
#define NROWS 8192
#define NOUT 512
#define NTOT (4294967296.0/128.0)  // unused; real n below

static const float SQRT_HALF_F = 0.70710678118654752440f;

typedef __attribute__((ext_vector_type(8))) short short8;
typedef __attribute__((ext_vector_type(4))) float f32x4;

// ws layout
#define A_OFF   0ull                                  // fp32 A: 8192*4096*4 = 134217728
#define WT_OFF  134217728ull                          // bf16 Wt: 512*4096*2 = 4194304
#define ST_OFF  (WT_OFF + 4194304ull)                 // double[2]
#define THR_OFF (ST_OFF + 16ull)                      // float[1]

__device__ inline unsigned short f2bf(float f) {
  union { float f; unsigned u; } v; v.f = f;
  unsigned r = (v.u + 0x7fffu + ((v.u >> 16) & 1u)) >> 16;
  return (unsigned short)r;
}

__device__ inline void async16(void* l, const void* g) {
  __builtin_amdgcn_global_load_lds((const __attribute__((address_space(1))) void*)g,
                                   (__attribute__((address_space(3))) void*)l, 16, 0, 0);
}

// ---------------- Kernel 1: Haar 5-level + stats ----------------
__global__ __launch_bounds__(256) void haar_kernel(const float* __restrict__ x,
                                                   float* __restrict__ A,
                                                   double* __restrict__ stats) {
  __shared__ __align__(16) float bufA[4096];
  __shared__ __align__(16) float bufB[2048];
  __shared__ double red[8];

  const int row = blockIdx.x;
  const int tid = threadIdx.x;
  const float S = SQRT_HALF_F;

  const float4* xr = (const float4*)(x + (size_t)row * LDIM);
  float4* bA4 = (float4*)bufA;
#pragma unroll
  for (int k = 0; k < 4; ++k) bA4[tid + k * 256] = xr[tid + k * 256];
  __syncthreads();

  float* out = A + (size_t)row * LDIM;
  double sa = 0.0, sq = 0.0;

  // level 1: bufA(4096) -> details out[2048..4096), approx bufB(2048)
#pragma unroll
  for (int k = 0; k < 8; ++k) {
    int i = tid + k * 256;
    float e = bufA[2 * i], o = bufA[2 * i + 1];
    float d = (e - o) * S, ap = (e + o) * S;
    out[2048 + i] = d; sa += (double)fabsf(d); sq += (double)d * (double)d;
    bufB[i] = ap;
  }
  __syncthreads();
  // level 2: bufB(2048) -> out[1024..2048), bufA(1024)
#pragma unroll
  for (int k = 0; k < 4; ++k) {
    int i = tid + k * 256;
    float e = bufB[2 * i], o = bufB[2 * i + 1];
    float d = (e - o) * S, ap = (e + o) * S;
    out[1024 + i] = d; sa += (double)fabsf(d); sq += (double)d * (double)d;
    bufA[i] = ap;
  }
  __syncthreads();
  // level 3: bufA(1024) -> out[512..1024), bufB(512)
#pragma unroll
  for (int k = 0; k < 2; ++k) {
    int i = tid + k * 256;
    float e = bufA[2 * i], o = bufA[2 * i + 1];
    float d = (e - o) * S, ap = (e + o) * S;
    out[512 + i] = d; sa += (double)fabsf(d); sq += (double)d * (double)d;
    bufB[i] = ap;
  }
  __syncthreads();
  // level 4: bufB(512) -> out[256..512), bufA(256)
  {
    int i = tid;
    float e = bufB[2 * i], o = bufB[2 * i + 1];
    float d = (e - o) * S, ap = (e + o) * S;
    out[256 + i] = d; sa += (double)fabsf(d); sq += (double)d * (double)d;
    bufA[i] = ap;
  }
  __syncthreads();
  // level 5: bufA(256) -> out[128..256) details, out[0..128) approx
  if (tid < 128) {
    int i = tid;
    float e = bufA[2 * i], o = bufA[2 * i + 1];
    float d = (e - o) * S, ap = (e + o) * S;
    out[128 + i] = d; out[i] = ap;
    sa += (double)fabsf(d) + (double)fabsf(ap);
    sq += (double)d * (double)d + (double)ap * (double)ap;
  }

  // block reduction
  const int lane = tid & 63, wid = tid >> 6;
#pragma unroll
  for (int off = 32; off > 0; off >>= 1) {
    sa += __shfl_down(sa, off, 64);
    sq += __shfl_down(sq, off, 64);
  }
  if (lane == 0) { red[wid] = sa; red[4 + wid] = sq; }
  __syncthreads();
  if (tid == 0) {
    double s = red[0] + red[1] + red[2] + red[3];
    double q = red[4] + red[5] + red[6] + red[7];
    atomicAdd(&stats[0], s);
    atomicAdd(&stats[1], q);
  }
}

// ---------------- Kernel 2: W (K x N fp32) -> Wt (N x K bf16) ----------------
__global__ __launch_bounds__(256) void wcvt_kernel(const float* __restrict__ W,
                                                   unsigned short* __restrict__ Wt) {
  __shared__ float tile[32][33];
  const int bx = blockIdx.x;   // n tile: 0..15
  const int by = blockIdx.y;   // k tile: 0..127
  const int tx = threadIdx.x & 31, ty = threadIdx.x >> 5;  // 32 x 8
#pragma unroll
  for (int j = 0; j < 4; ++j)
    tile[ty + j * 8][tx] = W[(size_t)(by * 32 + ty + j * 8) * NOUT + bx * 32 + tx];
  __syncthreads();
#pragma unroll
  for (int j = 0; j < 4; ++j)
    Wt[(size_t)(bx * 32 + ty + j * 8) * LDIM + by * 32 + tx] = f2bf(tile[tx][ty + j * 8]);
}

// ---------------- Kernel 3: threshold scalar ----------------
__global__ void thr_kernel(const double* __restrict__ stats, float* __restrict__ thr) {
  const double n = (double)NROWS * (double)LDIM;
  double mean = stats[0] / n;
  double var = (stats[1] - stats[0] * stats[0] / n) / (n - 1.0);
  *thr = (float)(mean + sqrt(var));
}

// ---------------- Kernel 4: masked bf16 MFMA GEMM + ReLU ----------------
// C[8192x512] = relu( mask(A[8192x4096]) @ W[4096x512] ), tiles 128x128, BK=32
__global__ __launch_bounds__(256) void gemm_kernel(const float* __restrict__ A,
                                                   const unsigned short* __restrict__ Wt,
                                                   const float* __restrict__ thrp,
                                                   float* __restrict__ out) {
  __shared__ __align__(16) unsigned short As[128 * 56];  // padded stride 56
  __shared__ __align__(16) unsigned short Bs[128 * 32];  // DMA, unpadded

  const float thr = *thrp;
  const int tid = threadIdx.x;
  const int lane = tid & 63, wid = tid >> 6;
  const int quad = lane >> 4, l15 = lane & 15;
  const int wm = wid >> 1, wn = wid & 1;
  const int n0 = blockIdx.x * 128;
  const int m0 = blockIdx.y * 128;

  f32x4 acc[4][4] = {};

  const int arow = tid >> 1, aseg = tid & 1;
  const float* Ag = A + (size_t)(m0 + arow) * LDIM + aseg * 16;

  // B DMA source: group = wid*2 + c covers 16 n-rows; lane covers 8 bf16 of k
  const unsigned short* Bg0 =
      Wt + (size_t)(n0 + wid * 32 + (lane >> 2)) * LDIM + (lane & 3) * 8;
  const unsigned short* Bg1 = Bg0 + (size_t)16 * LDIM;
  unsigned short* BsBase0 = &Bs[(wid * 2 + 0) * 16 * 32];
  unsigned short* BsBase1 = &Bs[(wid * 2 + 1) * 16 * 32];

  for (int k0 = 0; k0 < LDIM; k0 += 32) {
    // B tile: 128x32 bf16 via direct-to-LDS DMA (2 calls per wave)
    async16(BsBase0, Bg0 + k0);
    async16(BsBase1, Bg1 + k0);

    // A tile: fp32 load -> mask -> bf16 -> LDS (each thread: 16 floats)
    const float* ag = Ag + k0;
    float xv[16];
#pragma unroll
    for (int i = 0; i < 16; i += 4) {
      float4 t = *(const float4*)(ag + i);
      xv[i] = t.x; xv[i + 1] = t.y; xv[i + 2] = t.z; xv[i + 3] = t.w;
    }
    short8 s0, s1;
#pragma unroll
    for (int i = 0; i < 8; ++i) {
      float f = xv[i];
      f = (fabsf(f) > thr) ? f : 0.0f;
      s0[i] = (short)f2bf(f);
    }
#pragma unroll
    for (int i = 0; i < 8; ++i) {
      float f = xv[8 + i];
      f = (fabsf(f) > thr) ? f : 0.0f;
      s1[i] = (short)f2bf(f);
    }
    unsigned short* dst = &As[arow * 56 + aseg * 16];
    *(short8*)(dst) = s0;
    *(short8*)(dst + 8) = s1;

    __syncthreads();  // drains vmcnt (DMA) + lgkmcnt (ds_write)

    short8 af[4], bfr[4];
#pragma unroll
    for (int mi = 0; mi < 4; ++mi)
      af[mi] = *(const short8*)&As[(wm * 64 + mi * 16 + l15) * 56 + quad * 8];
#pragma unroll
    for (int ni = 0; ni < 4; ++ni)
      bfr[ni] = *(const short8*)&Bs[(wn * 64 + ni * 16 + l15) * 32 + quad * 8];
#pragma unroll
    for (int mi = 0; mi < 4; ++mi)
#pragma unroll
      for (int ni = 0; ni < 4; ++ni)
        acc[mi][ni] = __builtin_amdgcn_mfma_f32_16x16x32_bf16(af[mi], bfr[ni], acc[mi][ni], 0, 0, 0);

    __syncthreads();
  }

  // epilogue: C/D layout col = lane&15, row = quad*4 + reg
#pragma unroll
  for (int mi = 0; mi < 4; ++mi) {
#pragma unroll
    for (int ni = 0; ni < 4; ++ni) {
      const int r0 = m0 + wm * 64 + mi * 16 + quad * 4;
      const int c = n0 + wn * 64 + ni * 16 + l15;
#pragma unroll
      for (int r = 0; r < 4; ++r)
        out[(size_t)(r0 + r) * NOUT + c] = fmaxf(acc[mi][ni][r], 0.0f);
    }
  }
}

extern "C" void kernel_launch(void* const* d_in, const int* in_sizes, int n_in,
                              void* d_out, int out_size, void* d_ws, size_t ws_size,
                              hipStream_t stream) {
  const float* x = (const float*)d_in[0];
  const float* W = (const float*)d_in[1];
  float* out = (float*)d_out;

  char* ws = (char*)d_ws;
  float* Abuf = (float*)(ws + A_OFF);
  unsigned short* Wt = (unsigned short*)(ws + WT_OFF);
  double* stats = (double*)(ws + ST_OFF);
  float* thr = (float*)(ws + THR_OFF);

  hipMemsetAsync(stats, 0, 16, stream);

  haar_kernel<<<NROWS, 256, 0, stream>>>(x, Abuf, stats);
  wcvt_kernel<<<dim3(NOUT / 32, LDIM / 32), 256, 0, stream>>>(W, Wt);
  thr_kernel<<<1, 1, 0, stream>>>(stats, thr);
  gemm_kernel<<<dim3(NOUT / 128, NROWS / 128), 256, 0, stream>>>(Abuf, Wt, thr, out);
}

// Round 2
// 339.169 us; speedup vs baseline: 1.5617x; 1.5617x over previous
//
#include <hip/hip_runtime.h>
#include <hip/hip_bf16.h>
#include <math.h>

#define LDIM 4096
#define NROWS 8192
#define NOUT 512

static const float SQRT_HALF_F = 0.70710678118654752440f;

typedef __attribute__((ext_vector_type(8))) short short8;
typedef __attribute__((ext_vector_type(4))) float f32x4;

// ws layout (total ~205.7 MB)
#define A_OFF    0ull                         // fp32 coeffs: 8192*4096*4 = 134217728
#define AM_OFF   134217728ull                 // bf16 masked A: 8192*4096*2 = 67108864
#define WT_OFF   (AM_OFF + 67108864ull)       // bf16 Wt (N x K): 512*4096*2 = 4194304
#define PART_OFF (WT_OFF + 4194304ull)        // double[8192*2] partials = 131072
#define THR_OFF  (PART_OFF + 131072ull)       // float[1]

__device__ inline unsigned short f2bf(float f) {
  union { float f; unsigned u; } v; v.f = f;
  unsigned r = (v.u + 0x7fffu + ((v.u >> 16) & 1u)) >> 16;
  return (unsigned short)r;
}

__device__ inline void async16(void* l, const void* g) {
  __builtin_amdgcn_global_load_lds((const __attribute__((address_space(1))) void*)g,
                                   (__attribute__((address_space(3))) void*)l, 16, 0, 0);
}

// ---------------- Kernel 1: Haar 5-level + per-block partial stats ----------------
__global__ __launch_bounds__(256) void haar_kernel(const float* __restrict__ x,
                                                   float* __restrict__ A,
                                                   double* __restrict__ partials) {
  __shared__ __align__(16) float bufA[4096];
  __shared__ __align__(16) float bufB[2048];
  __shared__ double red[8];

  const int row = blockIdx.x;
  const int tid = threadIdx.x;
  const float S = SQRT_HALF_F;

  const float4* xr = (const float4*)(x + (size_t)row * LDIM);
  float4* bA4 = (float4*)bufA;
#pragma unroll
  for (int k = 0; k < 4; ++k) bA4[tid + k * 256] = xr[tid + k * 256];
  __syncthreads();

  float* out = A + (size_t)row * LDIM;
  double sa = 0.0, sq = 0.0;

#pragma unroll
  for (int k = 0; k < 8; ++k) {
    int i = tid + k * 256;
    float e = bufA[2 * i], o = bufA[2 * i + 1];
    float d = (e - o) * S, ap = (e + o) * S;
    out[2048 + i] = d; sa += (double)fabsf(d); sq += (double)d * (double)d;
    bufB[i] = ap;
  }
  __syncthreads();
#pragma unroll
  for (int k = 0; k < 4; ++k) {
    int i = tid + k * 256;
    float e = bufB[2 * i], o = bufB[2 * i + 1];
    float d = (e - o) * S, ap = (e + o) * S;
    out[1024 + i] = d; sa += (double)fabsf(d); sq += (double)d * (double)d;
    bufA[i] = ap;
  }
  __syncthreads();
#pragma unroll
  for (int k = 0; k < 2; ++k) {
    int i = tid + k * 256;
    float e = bufA[2 * i], o = bufA[2 * i + 1];
    float d = (e - o) * S, ap = (e + o) * S;
    out[512 + i] = d; sa += (double)fabsf(d); sq += (double)d * (double)d;
    bufB[i] = ap;
  }
  __syncthreads();
  {
    int i = tid;
    float e = bufB[2 * i], o = bufB[2 * i + 1];
    float d = (e - o) * S, ap = (e + o) * S;
    out[256 + i] = d; sa += (double)fabsf(d); sq += (double)d * (double)d;
    bufA[i] = ap;
  }
  __syncthreads();
  if (tid < 128) {
    int i = tid;
    float e = bufA[2 * i], o = bufA[2 * i + 1];
    float d = (e - o) * S, ap = (e + o) * S;
    out[128 + i] = d; out[i] = ap;
    sa += (double)fabsf(d) + (double)fabsf(ap);
    sq += (double)d * (double)d + (double)ap * (double)ap;
  }

  const int lane = tid & 63, wid = tid >> 6;
#pragma unroll
  for (int off = 32; off > 0; off >>= 1) {
    sa += __shfl_down(sa, off, 64);
    sq += __shfl_down(sq, off, 64);
  }
  if (lane == 0) { red[wid] = sa; red[4 + wid] = sq; }
  __syncthreads();
  if (tid == 0) {
    // NO atomics: per-block partial store (round-1's 16384 same-line fp64
    // atomics serialized the whole kernel at 960 GB/s)
    partials[2 * (size_t)row + 0] = red[0] + red[1] + red[2] + red[3];
    partials[2 * (size_t)row + 1] = red[4] + red[5] + red[6] + red[7];
  }
}

// ---------------- Kernel 2: W (K x N fp32) -> Wt (N x K bf16) ----------------
__global__ __launch_bounds__(256) void wcvt_kernel(const float* __restrict__ W,
                                                   unsigned short* __restrict__ Wt) {
  __shared__ float tile[32][33];
  const int bx = blockIdx.x;   // n tile
  const int by = blockIdx.y;   // k tile
  const int tx = threadIdx.x & 31, ty = threadIdx.x >> 5;
#pragma unroll
  for (int j = 0; j < 4; ++j)
    tile[ty + j * 8][tx] = W[(size_t)(by * 32 + ty + j * 8) * NOUT + bx * 32 + tx];
  __syncthreads();
#pragma unroll
  for (int j = 0; j < 4; ++j)
    Wt[(size_t)(bx * 32 + ty + j * 8) * LDIM + by * 32 + tx] = f2bf(tile[tx][ty + j * 8]);
}

// ---------------- Kernel 3: reduce partials -> threshold ----------------
__global__ __launch_bounds__(256) void thr_kernel(const double* __restrict__ partials,
                                                  float* __restrict__ thr) {
  __shared__ double red[8];
  const int tid = threadIdx.x;
  double sa = 0.0, sq = 0.0;
#pragma unroll
  for (int k = 0; k < NROWS / 256; ++k) {
    int i = tid + k * 256;
    sa += partials[2 * i + 0];
    sq += partials[2 * i + 1];
  }
  const int lane = tid & 63, wid = tid >> 6;
#pragma unroll
  for (int off = 32; off > 0; off >>= 1) {
    sa += __shfl_down(sa, off, 64);
    sq += __shfl_down(sq, off, 64);
  }
  if (lane == 0) { red[wid] = sa; red[4 + wid] = sq; }
  __syncthreads();
  if (tid == 0) {
    double s = red[0] + red[1] + red[2] + red[3];
    double q = red[4] + red[5] + red[6] + red[7];
    const double n = (double)NROWS * (double)LDIM;
    double mean = s / n;
    double var = (q - s * s / n) / (n - 1.0);
    *thr = (float)(mean + sqrt(var));
  }
}

// ---------------- Kernel 4: mask + convert A fp32 -> bf16 (once) ----------------
__global__ __launch_bounds__(256) void mask_cvt_kernel(const float* __restrict__ A,
                                                       const float* __restrict__ thrp,
                                                       unsigned short* __restrict__ Am) {
  const float thr = *thrp;
  const size_t i0 = ((size_t)blockIdx.x * 256 + threadIdx.x) * 8;
  float4 t0 = *(const float4*)(A + i0);
  float4 t1 = *(const float4*)(A + i0 + 4);
  float xv[8] = {t0.x, t0.y, t0.z, t0.w, t1.x, t1.y, t1.z, t1.w};
  short8 s;
#pragma unroll
  for (int i = 0; i < 8; ++i) {
    float f = xv[i];
    f = (fabsf(f) > thr) ? f : 0.0f;
    s[i] = (short)f2bf(f);
  }
  *(short8*)(Am + i0) = s;
}

// ---------------- Kernel 5: bf16 MFMA GEMM + ReLU ----------------
// C[8192x512] = relu( Am[8192x4096] @ Wt^T ), tile 128m x 64n, BK=32
// All staging via global_load_lds width-16 DMA (m97 pattern). As/Bs stride
// 32 bf16 = 64 B rows -> 2-way LDS aliasing only (free, m136). Grid 512
// blocks -> 2 blocks/CU for cross-block latency hiding.
__global__ __launch_bounds__(256) void gemm_kernel(const unsigned short* __restrict__ Am,
                                                   const unsigned short* __restrict__ Wt,
                                                   float* __restrict__ out) {
  __shared__ __align__(16) unsigned short As[128 * 32];
  __shared__ __align__(16) unsigned short Bs[64 * 32];

  const int tid = threadIdx.x;
  const int lane = tid & 63, w = tid >> 6;
  const int quad = lane >> 4, l15 = lane & 15;
  const int n0 = blockIdx.x * 64;
  const int m0 = blockIdx.y * 128;

  f32x4 acc[2][4] = {};

  const int lrow = lane >> 2;          // 0..15
  const int lcol = (lane & 3) * 8;     // 0,8,16,24
  const unsigned short* Ag0 = Am + (size_t)(m0 + (w * 2 + 0) * 16 + lrow) * LDIM + lcol;
  const unsigned short* Ag1 = Am + (size_t)(m0 + (w * 2 + 1) * 16 + lrow) * LDIM + lcol;
  const unsigned short* Bg  = Wt + (size_t)(n0 + w * 16 + lrow) * LDIM + lcol;
  unsigned short* AsD0 = &As[(w * 2 + 0) * 512];
  unsigned short* AsD1 = &As[(w * 2 + 1) * 512];
  unsigned short* BsD  = &Bs[w * 512];

  for (int k0 = 0; k0 < LDIM; k0 += 32) {
    async16(AsD0, Ag0 + k0);
    async16(AsD1, Ag1 + k0);
    async16(BsD,  Bg  + k0);
    __syncthreads();  // compiler emits vmcnt(0) drain before s_barrier

    short8 af[2], bf[4];
#pragma unroll
    for (int mi = 0; mi < 2; ++mi)
      af[mi] = *(const short8*)&As[(w * 32 + mi * 16 + l15) * 32 + quad * 8];
#pragma unroll
    for (int ni = 0; ni < 4; ++ni)
      bf[ni] = *(const short8*)&Bs[(ni * 16 + l15) * 32 + quad * 8];
#pragma unroll
    for (int mi = 0; mi < 2; ++mi)
#pragma unroll
      for (int ni = 0; ni < 4; ++ni)
        acc[mi][ni] = __builtin_amdgcn_mfma_f32_16x16x32_bf16(af[mi], bf[ni], acc[mi][ni], 0, 0, 0);

    __syncthreads();
  }

  // C/D layout: col = lane&15, row = quad*4 + reg (verified round 0)
#pragma unroll
  for (int mi = 0; mi < 2; ++mi) {
#pragma unroll
    for (int ni = 0; ni < 4; ++ni) {
      const int r0 = m0 + w * 32 + mi * 16 + quad * 4;
      const int c = n0 + ni * 16 + l15;
#pragma unroll
      for (int r = 0; r < 4; ++r)
        out[(size_t)(r0 + r) * NOUT + c] = fmaxf(acc[mi][ni][r], 0.0f);
    }
  }
}

extern "C" void kernel_launch(void* const* d_in, const int* in_sizes, int n_in,
                              void* d_out, int out_size, void* d_ws, size_t ws_size,
                              hipStream_t stream) {
  const float* x = (const float*)d_in[0];
  const float* W = (const float*)d_in[1];
  float* out = (float*)d_out;

  char* ws = (char*)d_ws;
  float* Abuf = (float*)(ws + A_OFF);
  unsigned short* Am = (unsigned short*)(ws + AM_OFF);
  unsigned short* Wt = (unsigned short*)(ws + WT_OFF);
  double* partials = (double*)(ws + PART_OFF);
  float* thr = (float*)(ws + THR_OFF);

  haar_kernel<<<NROWS, 256, 0, stream>>>(x, Abuf, partials);
  wcvt_kernel<<<dim3(NOUT / 32, LDIM / 32), 256, 0, stream>>>(W, Wt);
  thr_kernel<<<1, 256, 0, stream>>>(partials, thr);
  mask_cvt_kernel<<<(NROWS * LDIM) / (256 * 8), 256, 0, stream>>>(Abuf, thr, Am);
  gemm_kernel<<<dim3(NOUT / 64, NROWS / 128), 256, 0, stream>>>(Am, Wt, out);
}

// Round 3
// 275.533 us; speedup vs baseline: 1.9224x; 1.2310x over previous
//
#include <hip/hip_runtime.h>
#include <hip/hip_bf16.h>
#include <math.h>

#define LDIM 4096
#define NROWS 8192
#define NOUT 512

static const float SQRT_HALF_F = 0.70710678118654752440f;

typedef __attribute__((ext_vector_type(8))) short short8;
typedef __attribute__((ext_vector_type(4))) float f32x4;

// ws layout
#define AM_OFF   0ull                         // bf16 masked A: 8192*4096*2 = 67108864
#define WT_OFF   67108864ull                  // bf16 Wt (N x K): 512*4096*2 = 4194304
#define PART_OFF (WT_OFF + 4194304ull)        // double[8192*2] partials
#define THR_OFF  (PART_OFF + 131072ull)       // float[1]

__device__ inline unsigned short f2bf(float f) {
  union { float f; unsigned u; } v; v.f = f;
  unsigned r = (v.u + 0x7fffu + ((v.u >> 16) & 1u)) >> 16;
  return (unsigned short)r;
}

__device__ inline void async16(void* l, const void* g) {
  __builtin_amdgcn_global_load_lds((const __attribute__((address_space(1))) void*)g,
                                   (__attribute__((address_space(3))) void*)l, 16, 0, 0);
}

// ---------------- Kernel 1: Haar 5-level, STATS ONLY (no coeff writes) ----------------
__global__ __launch_bounds__(256) void haar1_kernel(const float* __restrict__ x,
                                                    double* __restrict__ partials) {
  __shared__ __align__(16) float bufA[4096];
  __shared__ __align__(16) float bufB[2048];
  __shared__ double red[8];

  const int row = blockIdx.x;
  const int tid = threadIdx.x;
  const float S = SQRT_HALF_F;

  const float4* xr = (const float4*)(x + (size_t)row * LDIM);
  float4* bA4 = (float4*)bufA;
#pragma unroll
  for (int k = 0; k < 4; ++k) bA4[tid + k * 256] = xr[tid + k * 256];
  __syncthreads();

  double sa = 0.0, sq = 0.0;

#pragma unroll
  for (int k = 0; k < 8; ++k) {
    int i = tid + k * 256;
    float e = bufA[2 * i], o = bufA[2 * i + 1];
    float d = (e - o) * S, ap = (e + o) * S;
    sa += (double)fabsf(d); sq += (double)d * (double)d;
    bufB[i] = ap;
  }
  __syncthreads();
#pragma unroll
  for (int k = 0; k < 4; ++k) {
    int i = tid + k * 256;
    float e = bufB[2 * i], o = bufB[2 * i + 1];
    float d = (e - o) * S, ap = (e + o) * S;
    sa += (double)fabsf(d); sq += (double)d * (double)d;
    bufA[i] = ap;
  }
  __syncthreads();
#pragma unroll
  for (int k = 0; k < 2; ++k) {
    int i = tid + k * 256;
    float e = bufA[2 * i], o = bufA[2 * i + 1];
    float d = (e - o) * S, ap = (e + o) * S;
    sa += (double)fabsf(d); sq += (double)d * (double)d;
    bufB[i] = ap;
  }
  __syncthreads();
  {
    int i = tid;
    float e = bufB[2 * i], o = bufB[2 * i + 1];
    float d = (e - o) * S, ap = (e + o) * S;
    sa += (double)fabsf(d); sq += (double)d * (double)d;
    bufA[i] = ap;
  }
  __syncthreads();
  if (tid < 128) {
    int i = tid;
    float e = bufA[2 * i], o = bufA[2 * i + 1];
    float d = (e - o) * S, ap = (e + o) * S;
    sa += (double)fabsf(d) + (double)fabsf(ap);
    sq += (double)d * (double)d + (double)ap * (double)ap;
  }

  const int lane = tid & 63, wid = tid >> 6;
#pragma unroll
  for (int off = 32; off > 0; off >>= 1) {
    sa += __shfl_down(sa, off, 64);
    sq += __shfl_down(sq, off, 64);
  }
  if (lane == 0) { red[wid] = sa; red[4 + wid] = sq; }
  __syncthreads();
  if (tid == 0) {
    partials[2 * (size_t)row + 0] = red[0] + red[1] + red[2] + red[3];
    partials[2 * (size_t)row + 1] = red[4] + red[5] + red[6] + red[7];
  }
}

// ---------------- Kernel 2: reduce partials -> threshold ----------------
__global__ __launch_bounds__(256) void thr_kernel(const double* __restrict__ partials,
                                                  float* __restrict__ thr) {
  __shared__ double red[8];
  const int tid = threadIdx.x;
  double sa = 0.0, sq = 0.0;
#pragma unroll
  for (int k = 0; k < NROWS / 256; ++k) {
    int i = tid + k * 256;
    sa += partials[2 * i + 0];
    sq += partials[2 * i + 1];
  }
  const int lane = tid & 63, wid = tid >> 6;
#pragma unroll
  for (int off = 32; off > 0; off >>= 1) {
    sa += __shfl_down(sa, off, 64);
    sq += __shfl_down(sq, off, 64);
  }
  if (lane == 0) { red[wid] = sa; red[4 + wid] = sq; }
  __syncthreads();
  if (tid == 0) {
    double s = red[0] + red[1] + red[2] + red[3];
    double q = red[4] + red[5] + red[6] + red[7];
    const double n = (double)NROWS * (double)LDIM;
    double mean = s / n;
    double var = (q - s * s / n) / (n - 1.0);
    *thr = (float)(mean + sqrt(var));
  }
}

// ---------------- Kernel 3: Haar recompute + mask + bf16 write ----------------
__global__ __launch_bounds__(256) void haar2_kernel(const float* __restrict__ x,
                                                    const float* __restrict__ thrp,
                                                    unsigned short* __restrict__ Am) {
  __shared__ __align__(16) float bufA[4096];
  __shared__ __align__(16) float bufB[2048];
  __shared__ __align__(16) unsigned short rowD[4096];

  const float thr = *thrp;
  const int row = blockIdx.x;
  const int tid = threadIdx.x;
  const float S = SQRT_HALF_F;

  const float4* xr = (const float4*)(x + (size_t)row * LDIM);
  float4* bA4 = (float4*)bufA;
#pragma unroll
  for (int k = 0; k < 4; ++k) bA4[tid + k * 256] = xr[tid + k * 256];
  __syncthreads();

#pragma unroll
  for (int k = 0; k < 8; ++k) {
    int i = tid + k * 256;
    float e = bufA[2 * i], o = bufA[2 * i + 1];
    float d = (e - o) * S, ap = (e + o) * S;
    rowD[2048 + i] = f2bf((fabsf(d) > thr) ? d : 0.0f);
    bufB[i] = ap;
  }
  __syncthreads();
#pragma unroll
  for (int k = 0; k < 4; ++k) {
    int i = tid + k * 256;
    float e = bufB[2 * i], o = bufB[2 * i + 1];
    float d = (e - o) * S, ap = (e + o) * S;
    rowD[1024 + i] = f2bf((fabsf(d) > thr) ? d : 0.0f);
    bufA[i] = ap;
  }
  __syncthreads();
#pragma unroll
  for (int k = 0; k < 2; ++k) {
    int i = tid + k * 256;
    float e = bufA[2 * i], o = bufA[2 * i + 1];
    float d = (e - o) * S, ap = (e + o) * S;
    rowD[512 + i] = f2bf((fabsf(d) > thr) ? d : 0.0f);
    bufB[i] = ap;
  }
  __syncthreads();
  {
    int i = tid;
    float e = bufB[2 * i], o = bufB[2 * i + 1];
    float d = (e - o) * S, ap = (e + o) * S;
    rowD[256 + i] = f2bf((fabsf(d) > thr) ? d : 0.0f);
    bufA[i] = ap;
  }
  __syncthreads();
  if (tid < 128) {
    int i = tid;
    float e = bufA[2 * i], o = bufA[2 * i + 1];
    float d = (e - o) * S, ap = (e + o) * S;
    rowD[128 + i] = f2bf((fabsf(d) > thr) ? d : 0.0f);
    rowD[i] = f2bf((fabsf(ap) > thr) ? ap : 0.0f);
  }
  __syncthreads();

  // vectorized row store: 4096 bf16 = 8 KB, 2 x short8 per thread
  short8* dst = (short8*)(Am + (size_t)row * LDIM);
  const short8* src = (const short8*)rowD;
  dst[tid] = src[tid];
  dst[tid + 256] = src[tid + 256];
}

// ---------------- Kernel 4: W (K x N fp32) -> Wt (N x K bf16) ----------------
__global__ __launch_bounds__(256) void wcvt_kernel(const float* __restrict__ W,
                                                   unsigned short* __restrict__ Wt) {
  __shared__ float tile[32][33];
  const int bx = blockIdx.x;
  const int by = blockIdx.y;
  const int tx = threadIdx.x & 31, ty = threadIdx.x >> 5;
#pragma unroll
  for (int j = 0; j < 4; ++j)
    tile[ty + j * 8][tx] = W[(size_t)(by * 32 + ty + j * 8) * NOUT + bx * 32 + tx];
  __syncthreads();
#pragma unroll
  for (int j = 0; j < 4; ++j)
    Wt[(size_t)(bx * 32 + ty + j * 8) * LDIM + by * 32 + tx] = f2bf(tile[tx][ty + j * 8]);
}

// ---------------- Kernel 5: bf16 MFMA GEMM + ReLU ----------------
// C[8192x512] = relu( Am @ Wt^T ). Tile 128m x 64n, BK=64. 1-D grid of 512:
// xcd = id&7 (HW round-robin heuristic), mblk = (slot>>3)*8 + xcd so all 8
// n-blocks of one A-strip run concurrently on ONE XCD -> A strip L2-resident
// (round-2 FETCH was 286 MB = each XCD refetched all of A).
// LDS: 16-B chunk c of row r stored at position c^(r&7) (XOR swizzle via DMA
// *source* address) -> fragment ds_read_b128 spreads each quad across all 8
// chunk positions = 2-way bank aliasing only (free; round-2 stride-32 layout
// gave 6.29M conflicts).
__global__ __launch_bounds__(256) void gemm_kernel(const unsigned short* __restrict__ Am,
                                                   const unsigned short* __restrict__ Wt,
                                                   float* __restrict__ out) {
  __shared__ __align__(16) unsigned short As[128 * 64];  // 16 KB
  __shared__ __align__(16) unsigned short Bs[64 * 64];   //  8 KB

  const int tid = threadIdx.x;
  const int lane = tid & 63, w = tid >> 6;
  const int quad = lane >> 4, l15 = lane & 15;

  const int id = blockIdx.x;
  const int xcd = id & 7, slot = id >> 3;
  const int nblk = slot & 7;
  const int mblk = (slot >> 3) * 8 + xcd;
  const int n0 = nblk * 64, m0 = mblk * 128;

  f32x4 acc[2][4] = {};

  const int rl = lane >> 3;            // row within an 8-row DMA group
  const int cg = (lane & 7) ^ rl;      // XOR-swizzled source chunk index
  const unsigned short* AgBase = Am + (size_t)(m0 + rl) * LDIM + cg * 8;
  const unsigned short* BgBase = Wt + (size_t)(n0 + rl) * LDIM + cg * 8;

  for (int k0 = 0; k0 < LDIM; k0 += 64) {
#pragma unroll
    for (int j = 0; j < 4; ++j)
      async16(&As[(w * 4 + j) * 512], AgBase + (size_t)((w * 4 + j) * 8) * LDIM + k0);
#pragma unroll
    for (int j = 0; j < 2; ++j)
      async16(&Bs[(w * 2 + j) * 512], BgBase + (size_t)((w * 2 + j) * 8) * LDIM + k0);
    __syncthreads();

    short8 af[2][2], bf[4][2];
#pragma unroll
    for (int mi = 0; mi < 2; ++mi) {
      const int row = w * 32 + mi * 16 + l15;
#pragma unroll
      for (int ks = 0; ks < 2; ++ks)
        af[mi][ks] = *(const short8*)&As[row * 64 + ((ks * 4 + quad) ^ (row & 7)) * 8];
    }
#pragma unroll
    for (int ni = 0; ni < 4; ++ni) {
      const int row = ni * 16 + l15;
#pragma unroll
      for (int ks = 0; ks < 2; ++ks)
        bf[ni][ks] = *(const short8*)&Bs[row * 64 + ((ks * 4 + quad) ^ (row & 7)) * 8];
    }
#pragma unroll
    for (int ks = 0; ks < 2; ++ks)
#pragma unroll
      for (int mi = 0; mi < 2; ++mi)
#pragma unroll
        for (int ni = 0; ni < 4; ++ni)
          acc[mi][ni] = __builtin_amdgcn_mfma_f32_16x16x32_bf16(af[mi][ks], bf[ni][ks],
                                                                acc[mi][ni], 0, 0, 0);
    __syncthreads();
  }

  // C/D layout: col = lane&15, row = quad*4 + reg (verified rounds 1-2)
#pragma unroll
  for (int mi = 0; mi < 2; ++mi) {
#pragma unroll
    for (int ni = 0; ni < 4; ++ni) {
      const int r0 = m0 + w * 32 + mi * 16 + quad * 4;
      const int c = n0 + ni * 16 + l15;
#pragma unroll
      for (int r = 0; r < 4; ++r)
        out[(size_t)(r0 + r) * NOUT + c] = fmaxf(acc[mi][ni][r], 0.0f);
    }
  }
}

extern "C" void kernel_launch(void* const* d_in, const int* in_sizes, int n_in,
                              void* d_out, int out_size, void* d_ws, size_t ws_size,
                              hipStream_t stream) {
  const float* x = (const float*)d_in[0];
  const float* W = (const float*)d_in[1];
  float* out = (float*)d_out;

  char* ws = (char*)d_ws;
  unsigned short* Am = (unsigned short*)(ws + AM_OFF);
  unsigned short* Wt = (unsigned short*)(ws + WT_OFF);
  double* partials = (double*)(ws + PART_OFF);
  float* thr = (float*)(ws + THR_OFF);

  haar1_kernel<<<NROWS, 256, 0, stream>>>(x, partials);
  wcvt_kernel<<<dim3(NOUT / 32, LDIM / 32), 256, 0, stream>>>(W, Wt);
  thr_kernel<<<1, 256, 0, stream>>>(partials, thr);
  haar2_kernel<<<NROWS, 256, 0, stream>>>(x, thr, Am);
  gemm_kernel<<<512, 256, 0, stream>>>(Am, Wt, out);
}

// Round 4
// 273.926 us; speedup vs baseline: 1.9336x; 1.0059x over previous
//
#include <hip/hip_runtime.h>
#include <hip/hip_bf16.h>
#include <math.h>

#define LDIM 4096
#define NROWS 8192
#define NOUT 512

static const float SQRT_HALF_F = 0.70710678118654752440f;

typedef __attribute__((ext_vector_type(8))) short short8;
typedef __attribute__((ext_vector_type(4))) float f32x4;
typedef __attribute__((ext_vector_type(8))) unsigned short u16x8;
typedef __attribute__((ext_vector_type(4))) unsigned short u16x4;
typedef __attribute__((ext_vector_type(2))) unsigned short u16x2;

// ws layout
#define AM_OFF   0ull                         // bf16 masked A: 8192*4096*2 = 67108864
#define WT_OFF   67108864ull                  // bf16 Wt (N x K): 512*4096*2 = 4194304
#define PART_OFF (WT_OFF + 4194304ull)        // double[8192*2] partials
#define THR_OFF  (PART_OFF + 131072ull)       // float[1]

__device__ inline unsigned short f2bf(float f) {
  union { float f; unsigned u; } v; v.f = f;
  unsigned r = (v.u + 0x7fffu + ((v.u >> 16) & 1u)) >> 16;
  return (unsigned short)r;
}

__device__ inline unsigned short mcvt(float f, float thr) {
  return f2bf((fabsf(f) > thr) ? f : 0.0f);
}

__device__ inline void async16(void* l, const void* g) {
  __builtin_amdgcn_global_load_lds((const __attribute__((address_space(1))) void*)g,
                                   (__attribute__((address_space(3))) void*)l, 16, 0, 0);
}

// Register-resident 5-level Haar: thread t owns x[16t..16t+16); levels 1-4 are
// thread-local, level 5 is lane-pair (shfl_xor 1). No LDS staging, no mid-kernel
// barriers (round-3 version serialized on 5 syncthreads + stride-2 LDS reads).

// ---------------- Kernel 1: Haar stats only ----------------
__global__ __launch_bounds__(256) void haar1_kernel(const float* __restrict__ x,
                                                    double* __restrict__ partials) {
  __shared__ double red[8];
  const int row = blockIdx.x;
  const int t = threadIdx.x;
  const float S = SQRT_HALF_F;

  const float4* xr = (const float4*)(x + (size_t)row * LDIM) + 4 * t;
  float v[16];
#pragma unroll
  for (int k = 0; k < 4; ++k) {
    float4 q = xr[k];
    v[4 * k] = q.x; v[4 * k + 1] = q.y; v[4 * k + 2] = q.z; v[4 * k + 3] = q.w;
  }

  double sa = 0.0, sq = 0.0;
  float a1[8], a2[4], a3[2], a4;
#pragma unroll
  for (int j = 0; j < 8; ++j) {
    float d = (v[2 * j] - v[2 * j + 1]) * S;
    a1[j] = (v[2 * j] + v[2 * j + 1]) * S;
    sa += (double)fabsf(d); sq += (double)d * (double)d;
  }
#pragma unroll
  for (int j = 0; j < 4; ++j) {
    float d = (a1[2 * j] - a1[2 * j + 1]) * S;
    a2[j] = (a1[2 * j] + a1[2 * j + 1]) * S;
    sa += (double)fabsf(d); sq += (double)d * (double)d;
  }
#pragma unroll
  for (int j = 0; j < 2; ++j) {
    float d = (a2[2 * j] - a2[2 * j + 1]) * S;
    a3[j] = (a2[2 * j] + a2[2 * j + 1]) * S;
    sa += (double)fabsf(d); sq += (double)d * (double)d;
  }
  {
    float d = (a3[0] - a3[1]) * S;
    a4 = (a3[0] + a3[1]) * S;
    sa += (double)fabsf(d); sq += (double)d * (double)d;
  }
  {
    float other = __shfl_xor(a4, 1, 64);
    if ((t & 1) == 0) {
      float d = (a4 - other) * S, ap = (a4 + other) * S;
      sa += (double)fabsf(d) + (double)fabsf(ap);
      sq += (double)d * (double)d + (double)ap * (double)ap;
    }
  }

  const int lane = t & 63, wid = t >> 6;
#pragma unroll
  for (int off = 32; off > 0; off >>= 1) {
    sa += __shfl_down(sa, off, 64);
    sq += __shfl_down(sq, off, 64);
  }
  if (lane == 0) { red[wid] = sa; red[4 + wid] = sq; }
  __syncthreads();
  if (t == 0) {
    partials[2 * (size_t)row + 0] = red[0] + red[1] + red[2] + red[3];
    partials[2 * (size_t)row + 1] = red[4] + red[5] + red[6] + red[7];
  }
}

// ---------------- Kernel 2: reduce partials -> threshold ----------------
__global__ __launch_bounds__(256) void thr_kernel(const double* __restrict__ partials,
                                                  float* __restrict__ thr) {
  __shared__ double red[8];
  const int tid = threadIdx.x;
  double sa = 0.0, sq = 0.0;
#pragma unroll
  for (int k = 0; k < NROWS / 256; ++k) {
    int i = tid + k * 256;
    sa += partials[2 * i + 0];
    sq += partials[2 * i + 1];
  }
  const int lane = tid & 63, wid = tid >> 6;
#pragma unroll
  for (int off = 32; off > 0; off >>= 1) {
    sa += __shfl_down(sa, off, 64);
    sq += __shfl_down(sq, off, 64);
  }
  if (lane == 0) { red[wid] = sa; red[4 + wid] = sq; }
  __syncthreads();
  if (tid == 0) {
    double s = red[0] + red[1] + red[2] + red[3];
    double q = red[4] + red[5] + red[6] + red[7];
    const double n = (double)NROWS * (double)LDIM;
    double mean = s / n;
    double var = (q - s * s / n) / (n - 1.0);
    *thr = (float)(mean + sqrt(var));
  }
}

// ---------------- Kernel 3: Haar recompute + mask + bf16 write ----------------
__global__ __launch_bounds__(256) void haar2_kernel(const float* __restrict__ x,
                                                    const float* __restrict__ thrp,
                                                    unsigned short* __restrict__ Am) {
  const float thr = *thrp;
  const int row = blockIdx.x;
  const int t = threadIdx.x;
  const float S = SQRT_HALF_F;

  const float4* xr = (const float4*)(x + (size_t)row * LDIM) + 4 * t;
  float v[16];
#pragma unroll
  for (int k = 0; k < 4; ++k) {
    float4 q = xr[k];
    v[4 * k] = q.x; v[4 * k + 1] = q.y; v[4 * k + 2] = q.z; v[4 * k + 3] = q.w;
  }

  unsigned short* orow = Am + (size_t)row * LDIM;
  float a1[8], a2[4], a3[2], a4;

  u16x8 d1;
#pragma unroll
  for (int j = 0; j < 8; ++j) {
    float d = (v[2 * j] - v[2 * j + 1]) * S;
    a1[j] = (v[2 * j] + v[2 * j + 1]) * S;
    d1[j] = mcvt(d, thr);
  }
  *(u16x8*)(orow + 2048 + 8 * t) = d1;

  u16x4 d2;
#pragma unroll
  for (int j = 0; j < 4; ++j) {
    float d = (a1[2 * j] - a1[2 * j + 1]) * S;
    a2[j] = (a1[2 * j] + a1[2 * j + 1]) * S;
    d2[j] = mcvt(d, thr);
  }
  *(u16x4*)(orow + 1024 + 4 * t) = d2;

  u16x2 d3;
#pragma unroll
  for (int j = 0; j < 2; ++j) {
    float d = (a2[2 * j] - a2[2 * j + 1]) * S;
    a3[j] = (a2[2 * j] + a2[2 * j + 1]) * S;
    d3[j] = mcvt(d, thr);
  }
  *(u16x2*)(orow + 512 + 2 * t) = d3;

  {
    float d = (a3[0] - a3[1]) * S;
    a4 = (a3[0] + a3[1]) * S;
    orow[256 + t] = mcvt(d, thr);
  }
  {
    float other = __shfl_xor(a4, 1, 64);
    if ((t & 1) == 0) {
      float d = (a4 - other) * S, ap = (a4 + other) * S;
      orow[128 + t / 2] = mcvt(d, thr);
      orow[t / 2] = mcvt(ap, thr);
    }
  }
}

// ---------------- Kernel 4: W (K x N fp32) -> Wt (N x K bf16) ----------------
__global__ __launch_bounds__(256) void wcvt_kernel(const float* __restrict__ W,
                                                   unsigned short* __restrict__ Wt) {
  __shared__ float tile[32][33];
  const int bx = blockIdx.x;
  const int by = blockIdx.y;
  const int tx = threadIdx.x & 31, ty = threadIdx.x >> 5;
#pragma unroll
  for (int j = 0; j < 4; ++j)
    tile[ty + j * 8][tx] = W[(size_t)(by * 32 + ty + j * 8) * NOUT + bx * 32 + tx];
  __syncthreads();
#pragma unroll
  for (int j = 0; j < 4; ++j)
    Wt[(size_t)(bx * 32 + ty + j * 8) * LDIM + by * 32 + tx] = f2bf(tile[tx][ty + j * 8]);
}

// ---------------- Kernel 5: bf16 MFMA GEMM + ReLU ----------------
// C[8192x512] = relu( Am @ Wt^T ). Tile 128m x 64n, BK=64. 1-D grid of 512:
// xcd = id&7, mblk = (slot>>3)*8 + xcd so all 8 n-blocks of one A-strip run
// concurrently on ONE XCD -> A strip L2-resident. LDS XOR-8 chunk swizzle via
// DMA source address -> 2-way bank aliasing only (free).
__global__ __launch_bounds__(256) void gemm_kernel(const unsigned short* __restrict__ Am,
                                                   const unsigned short* __restrict__ Wt,
                                                   float* __restrict__ out) {
  __shared__ __align__(16) unsigned short As[128 * 64];  // 16 KB
  __shared__ __align__(16) unsigned short Bs[64 * 64];   //  8 KB

  const int tid = threadIdx.x;
  const int lane = tid & 63, w = tid >> 6;
  const int quad = lane >> 4, l15 = lane & 15;

  const int id = blockIdx.x;
  const int xcd = id & 7, slot = id >> 3;
  const int nblk = slot & 7;
  const int mblk = (slot >> 3) * 8 + xcd;
  const int n0 = nblk * 64, m0 = mblk * 128;

  f32x4 acc[2][4] = {};

  const int rl = lane >> 3;            // row within an 8-row DMA group
  const int cg = (lane & 7) ^ rl;      // XOR-swizzled source chunk index
  const unsigned short* AgBase = Am + (size_t)(m0 + rl) * LDIM + cg * 8;
  const unsigned short* BgBase = Wt + (size_t)(n0 + rl) * LDIM + cg * 8;

  for (int k0 = 0; k0 < LDIM; k0 += 64) {
#pragma unroll
    for (int j = 0; j < 4; ++j)
      async16(&As[(w * 4 + j) * 512], AgBase + (size_t)((w * 4 + j) * 8) * LDIM + k0);
#pragma unroll
    for (int j = 0; j < 2; ++j)
      async16(&Bs[(w * 2 + j) * 512], BgBase + (size_t)((w * 2 + j) * 8) * LDIM + k0);
    __syncthreads();

    short8 af[2][2], bf[4][2];
#pragma unroll
    for (int mi = 0; mi < 2; ++mi) {
      const int row = w * 32 + mi * 16 + l15;
#pragma unroll
      for (int ks = 0; ks < 2; ++ks)
        af[mi][ks] = *(const short8*)&As[row * 64 + ((ks * 4 + quad) ^ (row & 7)) * 8];
    }
#pragma unroll
    for (int ni = 0; ni < 4; ++ni) {
      const int row = ni * 16 + l15;
#pragma unroll
      for (int ks = 0; ks < 2; ++ks)
        bf[ni][ks] = *(const short8*)&Bs[row * 64 + ((ks * 4 + quad) ^ (row & 7)) * 8];
    }
#pragma unroll
    for (int ks = 0; ks < 2; ++ks)
#pragma unroll
      for (int mi = 0; mi < 2; ++mi)
#pragma unroll
        for (int ni = 0; ni < 4; ++ni)
          acc[mi][ni] = __builtin_amdgcn_mfma_f32_16x16x32_bf16(af[mi][ks], bf[ni][ks],
                                                                acc[mi][ni], 0, 0, 0);
    __syncthreads();
  }

  // C/D layout: col = lane&15, row = quad*4 + reg (verified rounds 1-3)
#pragma unroll
  for (int mi = 0; mi < 2; ++mi) {
#pragma unroll
    for (int ni = 0; ni < 4; ++ni) {
      const int r0 = m0 + w * 32 + mi * 16 + quad * 4;
      const int c = n0 + ni * 16 + l15;
#pragma unroll
      for (int r = 0; r < 4; ++r)
        out[(size_t)(r0 + r) * NOUT + c] = fmaxf(acc[mi][ni][r], 0.0f);
    }
  }
}

extern "C" void kernel_launch(void* const* d_in, const int* in_sizes, int n_in,
                              void* d_out, int out_size, void* d_ws, size_t ws_size,
                              hipStream_t stream) {
  const float* x = (const float*)d_in[0];
  const float* W = (const float*)d_in[1];
  float* out = (float*)d_out;

  char* ws = (char*)d_ws;
  unsigned short* Am = (unsigned short*)(ws + AM_OFF);
  unsigned short* Wt = (unsigned short*)(ws + WT_OFF);
  double* partials = (double*)(ws + PART_OFF);
  float* thr = (float*)(ws + THR_OFF);

  haar1_kernel<<<NROWS, 256, 0, stream>>>(x, partials);
  wcvt_kernel<<<dim3(NOUT / 32, LDIM / 32), 256, 0, stream>>>(W, Wt);
  thr_kernel<<<1, 256, 0, stream>>>(partials, thr);
  haar2_kernel<<<NROWS, 256, 0, stream>>>(x, thr, Am);
  gemm_kernel<<<512, 256, 0, stream>>>(Am, Wt, out);
}

// Round 5
// 268.001 us; speedup vs baseline: 1.9764x; 1.0221x over previous
//
#include <hip/hip_runtime.h>
#include <hip/hip_bf16.h>
#include <math.h>

#define LDIM 4096
#define NROWS 8192
#define NOUT 512

static const float SQRT_HALF_F = 0.70710678118654752440f;

typedef __attribute__((ext_vector_type(8))) short short8;
typedef __attribute__((ext_vector_type(4))) float f32x4;
typedef __attribute__((ext_vector_type(8))) unsigned short u16x8;
typedef __attribute__((ext_vector_type(4))) unsigned short u16x4;
typedef __attribute__((ext_vector_type(2))) unsigned short u16x2;

// ws layout
#define AM_OFF   0ull                         // bf16 masked A: 8192*4096*2 = 67108864
#define WT_OFF   67108864ull                  // bf16 Wt (N x K): 512*4096*2 = 4194304
#define PART_OFF (WT_OFF + 4194304ull)        // double[8192*2] partials
#define THR_OFF  (PART_OFF + 131072ull)       // float[1]

__device__ inline unsigned short f2bf(float f) {
  union { float f; unsigned u; } v; v.f = f;
  unsigned r = (v.u + 0x7fffu + ((v.u >> 16) & 1u)) >> 16;
  return (unsigned short)r;
}

__device__ inline unsigned short mcvt(float f, float thr) {
  return f2bf((fabsf(f) > thr) ? f : 0.0f);
}

__device__ inline void async16(void* l, const void* g) {
  __builtin_amdgcn_global_load_lds((const __attribute__((address_space(1))) void*)g,
                                   (__attribute__((address_space(3))) void*)l, 16, 0, 0);
}

// ---------------- Kernel 1: Haar stats (blocks 0..8191) + W convert (tail) ----
// Register-resident 5-level Haar: thread t owns x[16t..16t+16); levels 1-4
// thread-local, level 5 lane-pair (shfl_xor 1). wcvt fused as tail blocks to
// save one launch (in-stream kernels serialize; wcvt was pure added latency).
__global__ __launch_bounds__(256) void haar1_kernel(const float* __restrict__ x,
                                                    double* __restrict__ partials,
                                                    const float* __restrict__ W,
                                                    unsigned short* __restrict__ Wt) {
  if (blockIdx.x >= NROWS) {
    // ---- fused wcvt: W (K x N fp32) -> Wt (N x K bf16) ----
    __shared__ float tile[32][33];
    const int wb = blockIdx.x - NROWS;
    const int bx = wb & 15;        // n tile (16)
    const int by = wb >> 4;        // k tile (128)
    const int tx = threadIdx.x & 31, ty = threadIdx.x >> 5;
#pragma unroll
    for (int j = 0; j < 4; ++j)
      tile[ty + j * 8][tx] = W[(size_t)(by * 32 + ty + j * 8) * NOUT + bx * 32 + tx];
    __syncthreads();
#pragma unroll
    for (int j = 0; j < 4; ++j)
      Wt[(size_t)(bx * 32 + ty + j * 8) * LDIM + by * 32 + tx] = f2bf(tile[tx][ty + j * 8]);
    return;
  }

  __shared__ double red[8];
  const int row = blockIdx.x;
  const int t = threadIdx.x;
  const float S = SQRT_HALF_F;

  const float4* xr = (const float4*)(x + (size_t)row * LDIM) + 4 * t;
  float v[16];
#pragma unroll
  for (int k = 0; k < 4; ++k) {
    float4 q = xr[k];
    v[4 * k] = q.x; v[4 * k + 1] = q.y; v[4 * k + 2] = q.z; v[4 * k + 3] = q.w;
  }

  double sa = 0.0, sq = 0.0;
  float a1[8], a2[4], a3[2], a4;
#pragma unroll
  for (int j = 0; j < 8; ++j) {
    float d = (v[2 * j] - v[2 * j + 1]) * S;
    a1[j] = (v[2 * j] + v[2 * j + 1]) * S;
    sa += (double)fabsf(d); sq += (double)d * (double)d;
  }
#pragma unroll
  for (int j = 0; j < 4; ++j) {
    float d = (a1[2 * j] - a1[2 * j + 1]) * S;
    a2[j] = (a1[2 * j] + a1[2 * j + 1]) * S;
    sa += (double)fabsf(d); sq += (double)d * (double)d;
  }
#pragma unroll
  for (int j = 0; j < 2; ++j) {
    float d = (a2[2 * j] - a2[2 * j + 1]) * S;
    a3[j] = (a2[2 * j] + a2[2 * j + 1]) * S;
    sa += (double)fabsf(d); sq += (double)d * (double)d;
  }
  {
    float d = (a3[0] - a3[1]) * S;
    a4 = (a3[0] + a3[1]) * S;
    sa += (double)fabsf(d); sq += (double)d * (double)d;
  }
  {
    float other = __shfl_xor(a4, 1, 64);
    if ((t & 1) == 0) {
      float d = (a4 - other) * S, ap = (a4 + other) * S;
      sa += (double)fabsf(d) + (double)fabsf(ap);
      sq += (double)d * (double)d + (double)ap * (double)ap;
    }
  }

  const int lane = t & 63, wid = t >> 6;
#pragma unroll
  for (int off = 32; off > 0; off >>= 1) {
    sa += __shfl_down(sa, off, 64);
    sq += __shfl_down(sq, off, 64);
  }
  if (lane == 0) { red[wid] = sa; red[4 + wid] = sq; }
  __syncthreads();
  if (t == 0) {
    partials[2 * (size_t)row + 0] = red[0] + red[1] + red[2] + red[3];
    partials[2 * (size_t)row + 1] = red[4] + red[5] + red[6] + red[7];
  }
}

// ---------------- Kernel 2: reduce partials -> threshold ----------------
__global__ __launch_bounds__(1024) void thr_kernel(const double* __restrict__ partials,
                                                   float* __restrict__ thr) {
  __shared__ double red[32];
  const int tid = threadIdx.x;
  double sa = 0.0, sq = 0.0;
#pragma unroll
  for (int k = 0; k < NROWS / 1024; ++k) {
    int i = tid + k * 1024;
    sa += partials[2 * i + 0];
    sq += partials[2 * i + 1];
  }
  const int lane = tid & 63, wid = tid >> 6;
#pragma unroll
  for (int off = 32; off > 0; off >>= 1) {
    sa += __shfl_down(sa, off, 64);
    sq += __shfl_down(sq, off, 64);
  }
  if (lane == 0) { red[wid] = sa; red[16 + wid] = sq; }
  __syncthreads();
  if (tid == 0) {
    double s = 0.0, q = 0.0;
#pragma unroll
    for (int i = 0; i < 16; ++i) { s += red[i]; q += red[16 + i]; }
    const double n = (double)NROWS * (double)LDIM;
    double mean = s / n;
    double var = (q - s * s / n) / (n - 1.0);
    *thr = (float)(mean + sqrt(var));
  }
}

// ---------------- Kernel 3: Haar recompute + mask + bf16 write ----------------
__global__ __launch_bounds__(256) void haar2_kernel(const float* __restrict__ x,
                                                    const float* __restrict__ thrp,
                                                    unsigned short* __restrict__ Am) {
  const float thr = *thrp;
  const int row = blockIdx.x;
  const int t = threadIdx.x;
  const float S = SQRT_HALF_F;

  const float4* xr = (const float4*)(x + (size_t)row * LDIM) + 4 * t;
  float v[16];
#pragma unroll
  for (int k = 0; k < 4; ++k) {
    float4 q = xr[k];
    v[4 * k] = q.x; v[4 * k + 1] = q.y; v[4 * k + 2] = q.z; v[4 * k + 3] = q.w;
  }

  unsigned short* orow = Am + (size_t)row * LDIM;
  float a1[8], a2[4], a3[2], a4;

  u16x8 d1;
#pragma unroll
  for (int j = 0; j < 8; ++j) {
    float d = (v[2 * j] - v[2 * j + 1]) * S;
    a1[j] = (v[2 * j] + v[2 * j + 1]) * S;
    d1[j] = mcvt(d, thr);
  }
  *(u16x8*)(orow + 2048 + 8 * t) = d1;

  u16x4 d2;
#pragma unroll
  for (int j = 0; j < 4; ++j) {
    float d = (a1[2 * j] - a1[2 * j + 1]) * S;
    a2[j] = (a1[2 * j] + a1[2 * j + 1]) * S;
    d2[j] = mcvt(d, thr);
  }
  *(u16x4*)(orow + 1024 + 4 * t) = d2;

  u16x2 d3;
#pragma unroll
  for (int j = 0; j < 2; ++j) {
    float d = (a2[2 * j] - a2[2 * j + 1]) * S;
    a3[j] = (a2[2 * j] + a2[2 * j + 1]) * S;
    d3[j] = mcvt(d, thr);
  }
  *(u16x2*)(orow + 512 + 2 * t) = d3;

  {
    float d = (a3[0] - a3[1]) * S;
    a4 = (a3[0] + a3[1]) * S;
    orow[256 + t] = mcvt(d, thr);
  }
  {
    float other = __shfl_xor(a4, 1, 64);
    if ((t & 1) == 0) {
      float d = (a4 - other) * S, ap = (a4 + other) * S;
      orow[128 + t / 2] = mcvt(d, thr);
      orow[t / 2] = mcvt(ap, thr);
    }
  }
}

// ---------------- Kernel 4: bf16 MFMA GEMM + ReLU, 512 threads ----------------
// C[8192x512] = relu( Am @ Wt^T ). Tile 128m x 64n, BK=64, 8 waves/block
// (wave tile 32x32). 512-thread blocks x 2 blocks/CU = 4 waves/SIMD so the
// per-iteration vmcnt(0) barrier drain overlaps with other waves' MFMA
// (round-4 had 2 waves/SIMD -> drains exposed). 1-D grid of 512: xcd = id&7,
// mblk = (slot>>3)*8 + xcd -> all 8 n-blocks of an A-strip co-run on one XCD
// (A strip L2-resident). LDS XOR-8 chunk swizzle via DMA source address ->
// 2-way bank aliasing only.
__global__ __launch_bounds__(512) void gemm_kernel(const unsigned short* __restrict__ Am,
                                                   const unsigned short* __restrict__ Wt,
                                                   float* __restrict__ out) {
  __shared__ __align__(16) unsigned short As[128 * 64];  // 16 KB
  __shared__ __align__(16) unsigned short Bs[64 * 64];   //  8 KB

  const int tid = threadIdx.x;
  const int lane = tid & 63, w = tid >> 6;      // 8 waves
  const int quad = lane >> 4, l15 = lane & 15;
  const int wm = w >> 1, wn = w & 1;            // 4 x 2 wave grid

  const int id = blockIdx.x;
  const int xcd = id & 7, slot = id >> 3;
  const int nblk = slot & 7;
  const int mblk = (slot >> 3) * 8 + xcd;
  const int n0 = nblk * 64, m0 = mblk * 128;

  f32x4 acc[2][2] = {};

  const int rl = lane >> 3;            // row within an 8-row DMA group
  const int cg = (lane & 7) ^ rl;      // XOR-swizzled source chunk index
  const unsigned short* AgBase = Am + (size_t)(m0 + rl) * LDIM + cg * 8;
  const unsigned short* BgBase = Wt + (size_t)(n0 + rl) * LDIM + cg * 8;

  for (int k0 = 0; k0 < LDIM; k0 += 64) {
    // A: 128 rows, wave w covers rows (w*2+j)*8..+8, j=0,1
#pragma unroll
    for (int j = 0; j < 2; ++j)
      async16(&As[(w * 2 + j) * 512], AgBase + (size_t)((w * 2 + j) * 8) * LDIM + k0);
    // B: 64 rows, wave w covers rows w*8..+8
    async16(&Bs[w * 512], BgBase + (size_t)(w * 8) * LDIM + k0);
    __syncthreads();

    short8 af[2][2], bf[2][2];
#pragma unroll
    for (int mi = 0; mi < 2; ++mi) {
      const int row = wm * 32 + mi * 16 + l15;
#pragma unroll
      for (int ks = 0; ks < 2; ++ks)
        af[mi][ks] = *(const short8*)&As[row * 64 + ((ks * 4 + quad) ^ (row & 7)) * 8];
    }
#pragma unroll
    for (int ni = 0; ni < 2; ++ni) {
      const int row = wn * 32 + ni * 16 + l15;
#pragma unroll
      for (int ks = 0; ks < 2; ++ks)
        bf[ni][ks] = *(const short8*)&Bs[row * 64 + ((ks * 4 + quad) ^ (row & 7)) * 8];
    }
#pragma unroll
    for (int ks = 0; ks < 2; ++ks)
#pragma unroll
      for (int mi = 0; mi < 2; ++mi)
#pragma unroll
        for (int ni = 0; ni < 2; ++ni)
          acc[mi][ni] = __builtin_amdgcn_mfma_f32_16x16x32_bf16(af[mi][ks], bf[ni][ks],
                                                                acc[mi][ni], 0, 0, 0);
    __syncthreads();
  }

  // C/D layout: col = lane&15, row = quad*4 + reg (verified rounds 1-4)
#pragma unroll
  for (int mi = 0; mi < 2; ++mi) {
#pragma unroll
    for (int ni = 0; ni < 2; ++ni) {
      const int r0 = m0 + wm * 32 + mi * 16 + quad * 4;
      const int c = n0 + wn * 32 + ni * 16 + l15;
#pragma unroll
      for (int r = 0; r < 4; ++r)
        out[(size_t)(r0 + r) * NOUT + c] = fmaxf(acc[mi][ni][r], 0.0f);
    }
  }
}

extern "C" void kernel_launch(void* const* d_in, const int* in_sizes, int n_in,
                              void* d_out, int out_size, void* d_ws, size_t ws_size,
                              hipStream_t stream) {
  const float* x = (const float*)d_in[0];
  const float* W = (const float*)d_in[1];
  float* out = (float*)d_out;

  char* ws = (char*)d_ws;
  unsigned short* Am = (unsigned short*)(ws + AM_OFF);
  unsigned short* Wt = (unsigned short*)(ws + WT_OFF);
  double* partials = (double*)(ws + PART_OFF);
  float* thr = (float*)(ws + THR_OFF);

  haar1_kernel<<<NROWS + 2048, 256, 0, stream>>>(x, partials, W, Wt);
  thr_kernel<<<1, 1024, 0, stream>>>(partials, thr);
  haar2_kernel<<<NROWS, 256, 0, stream>>>(x, thr, Am);
  gemm_kernel<<<512, 512, 0, stream>>>(Am, Wt, out);
}